// Round 3
// baseline (9973.889 us; speedup 1.0000x reference)
//
#include <hip/hip_runtime.h>
#include <stdint.h>

#define TSTEPS 500
#define NB 128
#define NH 256
#define RINGN 32

typedef _Float16 f16;
typedef _Float16 f16x8 __attribute__((ext_vector_type(8)));
typedef float f32x4 __attribute__((ext_vector_type(4)));
typedef unsigned long long u64;
typedef unsigned int u32;

// ---------------- workspace layout ----------------
static constexpr size_t SZ_XCAT  = (size_t)TSTEPS*NB*256*2;      // [T][B][256] f16 (203 real + pad0)
static constexpr size_t SZ_WPACK = (size_t)6*8*128*512*2;        // [6][8][n=128][k=512] f16, swizzled image
static constexpr size_t SZ_BPACK = (size_t)6*8*128*4;            // f32 bias (forget +1 folded)
static constexpr size_t SZ_HBUF  = (size_t)6*RINGN*NB*NH*2;      // h ring [6][32][128][256] f16
static constexpr size_t SZ_FLAGS = (size_t)6*(TSTEPS+2)*32*4;    // per-wave flag slots (8wg x 4wv)
static constexpr size_t OFF_XCAT  = 0;
static constexpr size_t OFF_WPACK = OFF_XCAT + SZ_XCAT;
static constexpr size_t OFF_BPACK = OFF_WPACK + SZ_WPACK;
static constexpr size_t OFF_HBUF  = OFF_BPACK + SZ_BPACK;
static constexpr size_t OFF_FLAGS = OFF_HBUF + SZ_HBUF;
static constexpr size_t OFF_RNN   = (OFF_FLAGS + SZ_FLAGS + 255) & ~(size_t)255;
static constexpr size_t SZ_RNN    = (size_t)NB*512*4;            // [128][512] f32 (max over t of [hf;hb])
static constexpr size_t WS_NEED   = OFF_RNN + SZ_RNN;

// ---------------- prep: embed + concat + pad, cast f16 ----------------
__global__ void embed_kernel(const int* __restrict__ words,
                             const int* __restrict__ caps,
                             const float* __restrict__ emb,
                             const float* __restrict__ capt,
                             f16* __restrict__ xcat) {
  int t = blockIdx.x >> 7, b = blockIdx.x & 127, k = threadIdx.x;
  int w  = words[b*TSTEPS + t];
  int cp = caps [b*TSTEPS + t];
  float v = 0.f;
  if (k < 200)      v = emb[(size_t)w*200 + k];
  else if (k < 203) v = capt[cp*3 + (k-200)];
  xcat[((size_t)t*NB + b)*256 + k] = (f16)v;
}

// ---------------- prep: pack weights per (layer,wg) ----------------
// LDS image: column-major per n (k contiguous), 16B-block XOR swizzle:
//   elem(n,k) -> n*512 + (((k>>3) ^ (n&7))<<3) + (k&7)
// n (0..127): np=n>>6, g=(n>>4)&3 (gate i,j,f,o), lcn=n&15
//   -> original col = g*256 + wg*32 + np*16 + lcn   (unit = wg*32+np*16+lcn)
// k (0..511): k<256 = input rows (layer0: xcat rows 0..202, else h^{l-1}); k>=256 = own-h rows
__global__ void pack_kernel(const float* __restrict__ Wf0, const float* __restrict__ bf0,
                            const float* __restrict__ Wf1, const float* __restrict__ bf1,
                            const float* __restrict__ Wf2, const float* __restrict__ bf2,
                            const float* __restrict__ Wb0, const float* __restrict__ bb0,
                            const float* __restrict__ Wb1, const float* __restrict__ bb1,
                            const float* __restrict__ Wb2, const float* __restrict__ bb2,
                            f16* __restrict__ wpack, float* __restrict__ bpack) {
  int bid = blockIdx.x;
  int n = bid & 127, wg = (bid >> 7) & 7, layer = bid >> 10;
  const float* W; const float* bb;
  switch (layer) {
    case 0: W = Wf0; bb = bf0; break;
    case 1: W = Wf1; bb = bf1; break;
    case 2: W = Wf2; bb = bf2; break;
    case 3: W = Wb0; bb = bb0; break;
    case 4: W = Wb1; bb = bb1; break;
    default: W = Wb2; bb = bb2; break;
  }
  int level = layer % 3;
  int np = (n >> 6) & 1, g = (n >> 4) & 3, lcn = n & 15;
  int col = g*256 + wg*32 + np*16 + lcn;          // column in original [.,1024] W
  if (threadIdx.x == 0)
    bpack[((layer*8 + wg) << 7) + n] = bb[col] + (g == 2 ? 1.f : 0.f); // fold forget_bias
  size_t base = ((size_t)(layer*8 + wg)*128 + n)*512;
  for (int k = threadIdx.x; k < 512; k += 256) {
    int row;
    if (level == 0) row = (k < 203) ? k : ((k < 256) ? -1 : k - 53);  // -53: 256->203
    else            row = k;
    float v = (row < 0) ? 0.f : W[(size_t)row*1024 + col];
    int idx = (((k >> 3) ^ (n & 7)) << 3) + (k & 7);
    wpack[base + idx] = (f16)v;
  }
}

// ---------------- prep: flags + ring slot0 = h_0 = 0 ----------------
__global__ void init_kernel(int* __restrict__ flags, f16* __restrict__ hbuf) {
  int i = blockIdx.x*256 + threadIdx.x;
  if (i < 6*(TSTEPS+2)*32) {
    int r = i % ((TSTEPS+2)*32);
    flags[i] = (r < 32) ? 1 : 0;                   // t=0 ready for all layers/waves
  }
  if (i < 6*16384) {
    int l = i >> 14, e = i & 16383;
    ((unsigned int*)(hbuf + (size_t)l*RINGN*NB*NH))[e] = 0u;   // ring slot 0 = h_0 = 0
  }
}

// ---------------- helpers ----------------
__device__ __forceinline__ void pollv(const int* q) {   // all 64 lanes poll their own slot
  for (;;) {
    int v = __hip_atomic_load(q, __ATOMIC_RELAXED, __HIP_MEMORY_SCOPE_AGENT);
    if (__all(v != 0)) break;
    __builtin_amdgcn_s_sleep(1);
  }
}
__device__ __forceinline__ f16x8 ldA_coh(const f16* p) {   // 16B coherent (LLC) load as 2x u64
  union { u64 q[2]; f16x8 v; } u;
  u.q[0] = __hip_atomic_load((const u64*)p,     __ATOMIC_RELAXED, __HIP_MEMORY_SCOPE_AGENT);
  u.q[1] = __hip_atomic_load((const u64*)p + 1, __ATOMIC_RELAXED, __HIP_MEMORY_SCOPE_AGENT);
  return u.v;
}
__device__ __forceinline__ float sigf(float x) { return 1.f/(1.f + __expf(-x)); }
__device__ __forceinline__ float tanhf_(float x) {
  float e = __expf(-2.f*fabsf(x));
  float r = (1.f - e)/(1.f + e);
  return x < 0.f ? -r : r;
}

// grid = 48 (6 layers x 8 WGs), block = 256 (4 waves), dynLDS = 128KB weights.
// 2x2 wave decomposition: wave wv=(rg,cg) owns rows [rg*64,+64) x gate-cols [cg*64,+64)
// (cg picks units np=cg*16.. ; each lane has gates i,j,f,o of unit wg*32+cg*16+lc -> lane-local cell).
// Per iteration t (computing h_t):
//   poll own(t-1)+backpressure -> issue A-h loads -> x-GEMM(t) (hides LLC latency)
//   -> prefetch A-in(t+1) (prev flag one phase ahead) -> h-GEMM(t) -> cell -> store -> drain -> flag.
__global__ __launch_bounds__(256, 1)
void lstm_pipeline(const f16* __restrict__ xcat, const f16* __restrict__ wpack,
                   const float* __restrict__ bpack, f16* __restrict__ hbuf,
                   int* __restrict__ flags, float* __restrict__ rnn_out) {
  extern __shared__ char smem[];
  const int layer = blockIdx.x >> 3, wg = blockIdx.x & 7;
  const int stack = layer/3, level = layer - stack*3;

  { // weights -> LDS (swizzled image, linear copy)
    const uint4* src = (const uint4*)(wpack + (size_t)(layer*8 + wg)*128*512);
    uint4* dst = (uint4*)smem;
    for (int i = threadIdx.x; i < 8192; i += 256) dst[i] = src[i];
  }
  const int lane = threadIdx.x & 63, wv = threadIdx.x >> 6;
  const int lc = lane & 15, akg = lane >> 4, bx = lc & 7;
  const int rg = wv >> 1, cg = wv & 1;
  const int slot = wg*4 + wv;

  float bias[4];
  #pragma unroll
  for (int g = 0; g < 4; ++g)
    bias[g] = bpack[((layer*8 + wg) << 7) + cg*64 + g*16 + lc];
  __syncthreads();

  int*       fl_own  = flags + layer*(TSTEPS+2)*32;
  const int* fl_prev = flags + (layer-1)*(TSTEPS+2)*32;
  const int* fl_next = flags + (layer+1)*(TSTEPS+2)*32;
  const int* dummy0  = fl_own;                      // t=0 slots, always 1

  const int arow = rg*64 + lc;                      // A-frag base row (mt adds 16 each)

  float c_st[4][4], hmx[4][4];
  #pragma unroll
  for (int mt = 0; mt < 4; ++mt)
    #pragma unroll
    for (int r = 0; r < 4; ++r) { c_st[mt][r] = 0.f; hmx[mt][r] = -2.f; }

  f16x8 ain[4][8];                                  // A-in(t) fragments [mt][k8]

#define LOAD_AIN(T)                                                                         \
  do {                                                                                      \
    const f16* An_ = level ? (hbuf + ((size_t)(layer-1)*RINGN + (size_t)((T) & (RINGN-1)))*NB*NH) \
                           : (xcat + (size_t)(stack ? (TSTEPS - (T)) : ((T)-1))*NB*256);    \
    _Pragma("unroll")                                                                       \
    for (int mt = 0; mt < 4; ++mt)                                                          \
      _Pragma("unroll")                                                                     \
      for (int k8 = 0; k8 < 8; ++k8) {                                                      \
        const f16* p_ = An_ + (size_t)(arow + mt*16)*256 + k8*32 + akg*8;                   \
        ain[mt][k8] = level ? ldA_coh(p_) : *(const f16x8*)p_;                              \
      }                                                                                     \
  } while (0)

#define GEMM_HALF(AARR, HALF)                                                               \
    _Pragma("unroll")                                                                       \
    for (int k8 = 0; k8 < 8; ++k8) {                                                        \
      const int swz = (((HALF)*32 + k8*4 + akg) ^ bx) << 4;                                 \
      f16x8 vb0 = *(const f16x8*)(smem + (cg*64 + 0*16 + lc)*1024 + swz);                   \
      f16x8 vb1 = *(const f16x8*)(smem + (cg*64 + 1*16 + lc)*1024 + swz);                   \
      f16x8 vb2 = *(const f16x8*)(smem + (cg*64 + 2*16 + lc)*1024 + swz);                   \
      f16x8 vb3 = *(const f16x8*)(smem + (cg*64 + 3*16 + lc)*1024 + swz);                   \
      _Pragma("unroll")                                                                     \
      for (int mt = 0; mt < 4; ++mt) {                                                      \
        acc[mt][0] = __builtin_amdgcn_mfma_f32_16x16x32_f16(AARR[mt][k8], vb0, acc[mt][0],0,0,0); \
        acc[mt][1] = __builtin_amdgcn_mfma_f32_16x16x32_f16(AARR[mt][k8], vb1, acc[mt][1],0,0,0); \
        acc[mt][2] = __builtin_amdgcn_mfma_f32_16x16x32_f16(AARR[mt][k8], vb2, acc[mt][2],0,0,0); \
        acc[mt][3] = __builtin_amdgcn_mfma_f32_16x16x32_f16(AARR[mt][k8], vb3, acc[mt][3],0,0,0); \
      }                                                                                     \
    }

  // ---- preload A-in(1) ----
  if (level) {
    pollv(lane < 32 ? fl_prev + 1*32 + lane : dummy0 + (lane - 32));
    __builtin_amdgcn_sched_barrier(0);
    asm volatile("" ::: "memory");
  }
  LOAD_AIN(1);

  for (int t = 1; t <= TSTEPS; ++t) {
    // a. poll own(t-1) (lanes 0-31) + next-layer backpressure(t-33) (lanes 32-63)
    {
      const int* q;
      if (lane < 32)                      q = fl_own + (t-1)*32 + lane;
      else if (level < 2 && t >= 34)      q = fl_next + (t-33)*32 + (lane - 32);
      else                                q = dummy0 + (lane - 32);
      pollv(q);
      __builtin_amdgcn_sched_barrier(0);
      asm volatile("" ::: "memory");
    }

    // b. issue A-h(t-1) coherent loads (latency hidden under x-GEMM)
    const f16* Ah = hbuf + ((size_t)layer*RINGN + (size_t)((t-1) & (RINGN-1)))*NB*NH;
    f16x8 ah[4][8];
    #pragma unroll
    for (int mt = 0; mt < 4; ++mt)
      #pragma unroll
      for (int k8 = 0; k8 < 8; ++k8)
        ah[mt][k8] = ldA_coh(Ah + (size_t)(arow + mt*16)*256 + k8*32 + akg*8);

    // c. x-GEMM(t) (k-half 0 of B)
    f32x4 acc[4][4];
    #pragma unroll
    for (int mt = 0; mt < 4; ++mt)
      #pragma unroll
      for (int g = 0; g < 4; ++g) acc[mt][g] = (f32x4){0.f,0.f,0.f,0.f};
    GEMM_HALF(ain, 0)

    // d. prefetch A-in(t+1) (prev layer runs one phase ahead; usually no wait)
    if (t < TSTEPS) {
      if (level) {
        pollv(lane < 32 ? fl_prev + (t+1)*32 + lane : dummy0 + (lane - 32));
        __builtin_amdgcn_sched_barrier(0);
        asm volatile("" ::: "memory");
      }
      LOAD_AIN(t+1);
    }

    // e. h-GEMM(t) (k-half 1 of B; compiler waits ah as needed)
    GEMM_HALF(ah, 1)

    // f. cell update (lane-local) + coherent f16 stores (16 lanes -> 32B contiguous)
    f16* hout = hbuf + ((size_t)layer*RINGN + (size_t)(t & (RINGN-1)))*NB*NH;
    #pragma unroll
    for (int mt = 0; mt < 4; ++mt) {
      #pragma unroll
      for (int r = 0; r < 4; ++r) {
        int row = rg*64 + mt*16 + akg*4 + r;         // C/D: row=(lane>>4)*4+reg (+16*mt)
        float zi = acc[mt][0][r] + bias[0];
        float zj = acc[mt][1][r] + bias[1];
        float zf = acc[mt][2][r] + bias[2];          // +1 already folded
        float zo = acc[mt][3][r] + bias[3];
        float cs = sigf(zf)*c_st[mt][r] + sigf(zi)*tanhf_(zj);
        c_st[mt][r] = cs;
        float h = sigf(zo)*tanhf_(cs);
        if (level == 2) hmx[mt][r] = fmaxf(hmx[mt][r], h);
        union { f16 h; short s; } cv; cv.h = (f16)h;
        __hip_atomic_store((short*)(hout + (size_t)row*256 + wg*32 + cg*16 + lc), cv.s,
                           __ATOMIC_RELAXED, __HIP_MEMORY_SCOPE_AGENT);
      }
    }

    // g. drain (stores + prefetch loads) then post per-wave flag
    asm volatile("s_waitcnt vmcnt(0)" ::: "memory");
    if (lane == 0)
      __hip_atomic_store(&fl_own[t*32 + slot], t, __ATOMIC_RELAXED, __HIP_MEMORY_SCOPE_AGENT);
  }
#undef LOAD_AIN
#undef GEMM_HALF

  if (level == 2) {
    #pragma unroll
    for (int mt = 0; mt < 4; ++mt)
      #pragma unroll
      for (int r = 0; r < 4; ++r)
        rnn_out[(size_t)(rg*64 + mt*16 + akg*4 + r)*512 + stack*256 + wg*32 + cg*16 + lc]
            = hmx[mt][r];
  }
}

// ---------------- epilogue: elu(rnn@W1+b1)@W2+b2 -> sigmoid ----------------
__global__ __launch_bounds__(256)
void dense_kernel(const float* __restrict__ rnn, const float* __restrict__ W1,
                  const float* __restrict__ b1, const float* __restrict__ W2,
                  const float* __restrict__ b2, float* __restrict__ out) {
  __shared__ float h1[16][64];
  int r0 = blockIdx.x*16;
  int c = threadIdx.x & 63, rr = threadIdx.x >> 6;
  #pragma unroll
  for (int m = 0; m < 4; ++m) {
    int rl = rr*4 + m;
    const float* rp = rnn + (size_t)(r0 + rl)*512;
    float s = b1[c];
    for (int k = 0; k < 512; ++k) s = fmaf(rp[k], W1[(size_t)k*64 + c], s);
    h1[rl][c] = (s > 0.f) ? s : (__expf(s) - 1.f);
  }
  __syncthreads();
  if (threadIdx.x < 96) {
    int rl = threadIdx.x/6, cc = threadIdx.x - rl*6;
    float s = b2[cc];
    #pragma unroll
    for (int k = 0; k < 64; ++k) s = fmaf(h1[rl][k], W2[k*6 + cc], s);
    out[(size_t)(r0 + rl)*6 + cc] = 1.f/(1.f + __expf(-s));
  }
}

// ---------------- launch ----------------
extern "C" void kernel_launch(void* const* d_in, const int* in_sizes, int n_in,
                              void* d_out, int out_size, void* d_ws, size_t ws_size,
                              hipStream_t stream) {
  if (ws_size < WS_NEED) return;  // clean failure instead of corruption
  const int*   words = (const int*)d_in[0];
  const int*   caps  = (const int*)d_in[1];
  const float* emb   = (const float*)d_in[2];
  const float* capt  = (const float*)d_in[3];
  char* ws = (char*)d_ws;
  f16*   xcat  = (f16*)  (ws + OFF_XCAT);
  f16*   wpack = (f16*)  (ws + OFF_WPACK);
  float* bpack = (float*)(ws + OFF_BPACK);
  f16*   hbuf  = (f16*)  (ws + OFF_HBUF);
  int*   flags = (int*)  (ws + OFF_FLAGS);
  float* rnn   = (float*)(ws + OFF_RNN);

  embed_kernel<<<TSTEPS*NB, 256, 0, stream>>>(words, caps, emb, capt, xcat);
  pack_kernel<<<6*8*128, 256, 0, stream>>>(
      (const float*)d_in[4],  (const float*)d_in[5],  (const float*)d_in[6],  (const float*)d_in[7],
      (const float*)d_in[8],  (const float*)d_in[9],  (const float*)d_in[10], (const float*)d_in[11],
      (const float*)d_in[12], (const float*)d_in[13], (const float*)d_in[14], (const float*)d_in[15],
      wpack, bpack);
  init_kernel<<<384, 256, 0, stream>>>(flags, hbuf);
  lstm_pipeline<<<48, 256, 131072, stream>>>(xcat, wpack, bpack, hbuf, flags, rnn);
  dense_kernel<<<8, 256, 0, stream>>>(rnn, (const float*)d_in[16], (const float*)d_in[17],
                                      (const float*)d_in[18], (const float*)d_in[19], (float*)d_out);
}

// Round 5
// 6343.287 us; speedup vs baseline: 1.5724x; 1.5724x over previous
//
#include <hip/hip_runtime.h>
#include <stdint.h>

#define TSTEPS 500
#define NB 128
#define NH 256
#define RINGN 8

typedef _Float16 f16;
typedef _Float16 f16x8 __attribute__((ext_vector_type(8)));
typedef float f32x4 __attribute__((ext_vector_type(4)));
typedef unsigned long long u64;
typedef unsigned int u32;

// ---------------- workspace layout ----------------
static constexpr size_t HSLOT = (size_t)NB*NH;                    // 32768 f16 per (layer,t) slot
static constexpr size_t SZ_XCAT  = (size_t)TSTEPS*NB*256*2;       // 32.77 MB
static constexpr size_t SZ_WPACK = (size_t)6*8*128*512*2;         // 6.29 MB
static constexpr size_t SZ_BPACK = (size_t)6*8*128*4;
static constexpr size_t SZ_HNEXT = (size_t)6*RINGN*HSLOT*2;       // 3.15 MB  (MALL-coherent ring)
static constexpr size_t SZ_HLOC  = (size_t)6*RINGN*HSLOT*2;       // 3.15 MB  (XCD-local L2 ring)
static constexpr size_t SZ_FLAGS = (size_t)6*(TSTEPS+1)*32*4;     // per-wave flags, value = xcc+1
static constexpr size_t SZ_RNN   = (size_t)NB*512*4;
static constexpr size_t OFF_XCAT  = 0;
static constexpr size_t OFF_WPACK = OFF_XCAT + SZ_XCAT;
static constexpr size_t OFF_BPACK = OFF_WPACK + SZ_WPACK;
static constexpr size_t OFF_HNEXT = OFF_BPACK + SZ_BPACK;
static constexpr size_t OFF_HLOC  = OFF_HNEXT + SZ_HNEXT;
static constexpr size_t OFF_FLAGS = OFF_HLOC + SZ_HLOC;
static constexpr size_t OFF_RNN   = (OFF_FLAGS + SZ_FLAGS + 255) & ~(size_t)255;
static constexpr size_t WS_NEED   = OFF_RNN + SZ_RNN;             // ~46 MB (< proven 52 MB budget)

// ---------------- prep: embed + concat + pad, cast f16 ----------------
__global__ void embed_kernel(const int* __restrict__ words,
                             const int* __restrict__ caps,
                             const float* __restrict__ emb,
                             const float* __restrict__ capt,
                             f16* __restrict__ xcat) {
  int t = blockIdx.x >> 7, b = blockIdx.x & 127, k = threadIdx.x;
  int w  = words[b*TSTEPS + t];
  int cp = caps [b*TSTEPS + t];
  float v = 0.f;
  if (k < 200)      v = emb[(size_t)w*200 + k];
  else if (k < 203) v = capt[cp*3 + (k-200)];
  xcat[((size_t)t*NB + b)*256 + k] = (f16)v;
}

// ---------------- prep: pack weights per (layer,wg) ----------------
// LDS image: column-major per n (k contiguous), 16B-block XOR swizzle:
//   elem(n,k) -> n*512 + (((k>>3) ^ (n&7))<<3) + (k&7)
// n (0..127): nt=n>>4 (gate=nt>>1, np=nt&1), lcn=n&15 -> unit = wg*32 + 2*lcn + np
// k (0..511): k<256 input rows (layer0: xcat 0..202; else prev h); k>=256 own-h rows
__global__ void pack_kernel(const float* __restrict__ Wf0, const float* __restrict__ bf0,
                            const float* __restrict__ Wf1, const float* __restrict__ bf1,
                            const float* __restrict__ Wf2, const float* __restrict__ bf2,
                            const float* __restrict__ Wb0, const float* __restrict__ bb0,
                            const float* __restrict__ Wb1, const float* __restrict__ bb1,
                            const float* __restrict__ Wb2, const float* __restrict__ bb2,
                            f16* __restrict__ wpack, float* __restrict__ bpack) {
  int bid = blockIdx.x;
  int n = bid & 127, wg = (bid >> 7) & 7, layer = bid >> 10;
  const float* W; const float* bb;
  switch (layer) {
    case 0: W = Wf0; bb = bf0; break;
    case 1: W = Wf1; bb = bf1; break;
    case 2: W = Wf2; bb = bf2; break;
    case 3: W = Wb0; bb = bb0; break;
    case 4: W = Wb1; bb = bb1; break;
    default: W = Wb2; bb = bb2; break;
  }
  int level = layer % 3;
  int nt = n >> 4, lcn = n & 15;
  int gate = nt >> 1, np = nt & 1;
  int col = gate*256 + wg*32 + 2*lcn + np;        // column in original [.,1024] W
  if (threadIdx.x == 0)
    bpack[((layer*8 + wg) << 7) + n] = bb[col] + (gate == 2 ? 1.f : 0.f); // fold forget_bias
  size_t base = ((size_t)(layer*8 + wg)*128 + n)*512;
  for (int k = threadIdx.x; k < 512; k += 256) {
    int row;
    if (level == 0) row = (k < 203) ? k : ((k < 256) ? -1 : k - 53);  // -53: 256->203
    else            row = k;
    float v = (row < 0) ? 0.f : W[(size_t)row*1024 + col];
    int idx = (((k >> 3) ^ (n & 7)) << 3) + (k & 7);
    wpack[base + idx] = (f16)v;
  }
}

// ---------------- prep: flags + hnext ring slot0 = h_0 = 0 ----------------
__global__ void init_kernel(int* __restrict__ flags, f16* __restrict__ hnext) {
  int i = blockIdx.x*256 + threadIdx.x;
  if (i < 6*(TSTEPS+1)*32) {
    int t = (i >> 5) % (TSTEPS+1);
    flags[i] = (t == 0) ? 9 : 0;                   // 9 = ready, never matches xcc+1 in [1,8]
  }
  if (i < 98304) {                                 // hnext slot 0 = zeros per layer
    int l = i >> 14, e = i & 16383;
    ((u32*)(hnext + (size_t)l*RINGN*HSLOT))[e] = 0u;
  }
}

// ---------------- helpers ----------------
__device__ __forceinline__ int pollv(const int* q) {     // per-lane slot; wave exits together
  int v;
  for (;;) {
    v = __hip_atomic_load(q, __ATOMIC_RELAXED, __HIP_MEMORY_SCOPE_AGENT);
    if (__all(v != 0)) break;
    __builtin_amdgcn_s_sleep(1);
  }
  return v;
}
__device__ __forceinline__ f16x8 ldA_coh(const f16* p) { // cross-XCD via MALL (proven R2 path)
  union { u64 q[2]; f16x8 v; } u;
  u.q[0] = __hip_atomic_load((const u64*)p,     __ATOMIC_RELAXED, __HIP_MEMORY_SCOPE_AGENT);
  u.q[1] = __hip_atomic_load((const u64*)p + 1, __ATOMIC_RELAXED, __HIP_MEMORY_SCOPE_AGENT);
  return u.v;
}
__device__ __forceinline__ f16x8 ld_a_l(const f16* p) {  // same-XCD: L1-bypass, L2-hit
  f16x8 v;
  asm volatile("global_load_dwordx4 %0, %1, off sc0" : "=v"(v) : "v"(p));
  return v;
}
__device__ __forceinline__ void vm_drain() {
  asm volatile("s_waitcnt vmcnt(0)" ::: "memory");
  __builtin_amdgcn_sched_barrier(0);
}
__device__ __forceinline__ u32 packh2(float a, float b) {
  union { f16 h[2]; u32 u; } x;
  x.h[0] = (f16)a; x.h[1] = (f16)b;
  return x.u;
}
__device__ __forceinline__ float sigf(float x) { return 1.f/(1.f + __expf(-x)); }
__device__ __forceinline__ float tanhf_(float x) {
  float e = __expf(-2.f*fabsf(x));
  float r = (1.f - e)/(1.f + e);
  return x < 0.f ? -r : r;
}

// grid = 64 (blockIdx = wg*8 + layer; layer>=6 exits), block = 256 (4 waves), dynLDS = 128KB.
// Wave wv owns rows [wv*32,+32) x ALL 128 gate-cols; the 4 wv-cohorts are independent pipelines.
// Flags carry producer xcc+1 -> per-step choice of L2-local (sc0, hloc) vs MALL (hnext) h loads.
__global__ __launch_bounds__(256, 1)
void lstm_pipeline(const f16* __restrict__ xcat, const f16* __restrict__ wpack,
                   const float* __restrict__ bpack, f16* hnext, f16* hloc,
                   int* flags, float* __restrict__ rnn_out) {
  const int layer = blockIdx.x & 7, wg = blockIdx.x >> 3;
  if (layer >= 6) return;
  extern __shared__ char smem[];
  const int stack = layer/3, level = layer - stack*3;

  { // weights -> LDS (swizzled image, linear copy)
    const uint4* src = (const uint4*)(wpack + (size_t)(layer*8 + wg)*128*512);
    uint4* dst = (uint4*)smem;
    for (int i = threadIdx.x; i < 8192; i += 256) dst[i] = src[i];
  }
  const int lane = threadIdx.x & 63, wv = threadIdx.x >> 6;
  const int lc = lane & 15, akg = lane >> 4, bx = lc & 7;
  const int xcp1 = ((int)__builtin_amdgcn_s_getreg((31 << 11) | 20) & 7) + 1;  // HW_REG_XCC_ID

  float bI[2], bJ[2], bF[2], bO[2];
  {
    const float* bb = bpack + ((size_t)(layer*8 + wg) << 7);
    #pragma unroll
    for (int np = 0; np < 2; ++np) {
      bI[np] = bb[(0*2 + np)*16 + lc];
      bJ[np] = bb[(1*2 + np)*16 + lc];
      bF[np] = bb[(2*2 + np)*16 + lc];
      bO[np] = bb[(3*2 + np)*16 + lc];
    }
  }
  __syncthreads();

  int*       flO = flags + (size_t)layer*(TSTEPS+1)*32;
  const int* flP = flags + (size_t)(layer-1)*(TSTEPS+1)*32;
  const int* flN = flags + (size_t)(layer+1)*(TSTEPS+1)*32;

  const size_t aoffL = ((size_t)(wv*32 + lc))*256 + (size_t)akg*8;

  float c_st[2][2][4], hmx[2][2][4];
  #pragma unroll
  for (int mt = 0; mt < 2; ++mt)
    #pragma unroll
    for (int np = 0; np < 2; ++np)
      #pragma unroll
      for (int r = 0; r < 4; ++r) { c_st[mt][np][r] = 0.f; hmx[mt][np][r] = -2.f; }

  for (int t = 1; t <= TSTEPS; ++t) {
    // ---- single merged poll round: own(t-1) | prev(t) | backpressure next(t-6) ----
    const int* q;
    if (lane < 8)                                   q = flO + (size_t)(t-1)*32 + lane*4 + wv;
    else if (lane < 16 && level)                    q = flP + (size_t)t*32 + (lane-8)*4 + wv;
    else if (lane >= 16 && lane < 24 && level < 2 && t > 6)
                                                    q = flN + (size_t)(t-6)*32 + (lane-16)*4 + wv;
    else                                            q = flO + ((lane*4 + wv) & 31);  // t=0, ==9
    int v = pollv(q);
    __builtin_amdgcn_sched_barrier(0);
    asm volatile("" ::: "memory");
    const bool own_l2  = __all(lane >= 8 || v == xcp1);
    const bool prev_l2 = __all(lane < 8 || lane >= 16 || v == xcp1) && (level != 0);

    // ---- cluster ALL A loads (input-half + recurrent-half) up front ----
    f16x8 aI0[8], aI1[8], aH0[8], aH1[8];
    if (level == 0) {
      const f16* Ain = xcat + (size_t)(stack ? (TSTEPS - t) : (t-1))*NB*256 + aoffL;
      #pragma unroll
      for (int k8 = 0; k8 < 8; ++k8) {
        aI0[k8] = *(const f16x8*)(Ain + k8*32);
        aI1[k8] = *(const f16x8*)(Ain + 16*256 + k8*32);
      }
    } else {
      const size_t off = ((size_t)(layer-1)*RINGN + (size_t)(t & (RINGN-1)))*HSLOT + aoffL;
      if (prev_l2) {
        const f16* A = hloc + off;
        #pragma unroll
        for (int k8 = 0; k8 < 8; ++k8) {
          aI0[k8] = ld_a_l(A + k8*32);
          aI1[k8] = ld_a_l(A + 16*256 + k8*32);
        }
      } else {
        const f16* A = hnext + off;
        #pragma unroll
        for (int k8 = 0; k8 < 8; ++k8) {
          aI0[k8] = ldA_coh(A + k8*32);
          aI1[k8] = ldA_coh(A + 16*256 + k8*32);
        }
      }
    }
    {
      const size_t off = ((size_t)layer*RINGN + (size_t)((t-1) & (RINGN-1)))*HSLOT + aoffL;
      if (own_l2) {
        const f16* A = hloc + off;
        #pragma unroll
        for (int k8 = 0; k8 < 8; ++k8) {
          aH0[k8] = ld_a_l(A + k8*32);
          aH1[k8] = ld_a_l(A + 16*256 + k8*32);
        }
      } else {
        const f16* A = hnext + off;
        #pragma unroll
        for (int k8 = 0; k8 < 8; ++k8) {
          aH0[k8] = ldA_coh(A + k8*32);
          aH1[k8] = ldA_coh(A + 16*256 + k8*32);
        }
      }
    }
    vm_drain();   // asm-loaded regs valid before MFMA consumes them (rule #18)

    f32x4 acc[2][8];
    #pragma unroll
    for (int mt = 0; mt < 2; ++mt)
      #pragma unroll
      for (int nt = 0; nt < 8; ++nt) acc[mt][nt] = (f32x4){0.f,0.f,0.f,0.f};

    #pragma unroll
    for (int k8 = 0; k8 < 8; ++k8) {
      const int swz0 = ((k8*4 + akg) ^ bx) << 4;          // input half   (kword 0..31)
      const int swz1 = ((32 + k8*4 + akg) ^ bx) << 4;     // recurrent half (kword 32..63)
      #pragma unroll
      for (int nt = 0; nt < 8; ++nt) {
        const char* base = smem + (nt*16 + lc)*1024;
        f16x8 vb0 = *(const f16x8*)(base + swz0);
        f16x8 vb1 = *(const f16x8*)(base + swz1);
        acc[0][nt] = __builtin_amdgcn_mfma_f32_16x16x32_f16(aI0[k8], vb0, acc[0][nt], 0,0,0);
        acc[1][nt] = __builtin_amdgcn_mfma_f32_16x16x32_f16(aI1[k8], vb0, acc[1][nt], 0,0,0);
        acc[0][nt] = __builtin_amdgcn_mfma_f32_16x16x32_f16(aH0[k8], vb1, acc[0][nt], 0,0,0);
        acc[1][nt] = __builtin_amdgcn_mfma_f32_16x16x32_f16(aH1[k8], vb1, acc[1][nt], 0,0,0);
      }
    }

    // ---- cell update (lane-local) + dual h store: plain->hloc (L2), atomic->hnext (MALL) ----
    const size_t obase = ((size_t)layer*RINGN + (size_t)(t & (RINGN-1)))*HSLOT;
    u32* hl32 = (u32*)(hloc  + obase);
    u32* hn32 = (u32*)(hnext + obase);
    #pragma unroll
    for (int mt = 0; mt < 2; ++mt) {
      #pragma unroll
      for (int r = 0; r < 4; ++r) {
        int row = wv*32 + mt*16 + akg*4 + r;               // C/D: row=(lane>>4)*4+reg (+16*mt)
        float hv[2];
        #pragma unroll
        for (int np = 0; np < 2; ++np) {
          float zi = acc[mt][0 + np][r] + bI[np];
          float zj = acc[mt][2 + np][r] + bJ[np];
          float zf = acc[mt][4 + np][r] + bF[np];          // +1 already folded
          float zo = acc[mt][6 + np][r] + bO[np];
          float cs = sigf(zf)*c_st[mt][np][r] + sigf(zi)*tanhf_(zj);
          c_st[mt][np][r] = cs;
          float h = sigf(zo)*tanhf_(cs);
          hv[np] = h;
          if (level == 2) hmx[mt][np][r] = fmaxf(hmx[mt][np][r], h);
        }
        u32 pk = packh2(hv[0], hv[1]);
        size_t idx = (size_t)row*128 + wg*16 + lc;
        hl32[idx] = pk;                                    // write-through to own XCD L2
        __hip_atomic_store(&hn32[idx], pk, __ATOMIC_RELAXED, __HIP_MEMORY_SCOPE_AGENT);
      }
    }
    vm_drain();                                            // both copies visible
    if (lane == 0)
      __hip_atomic_store(flO + (size_t)t*32 + wg*4 + wv, xcp1,
                         __ATOMIC_RELAXED, __HIP_MEMORY_SCOPE_AGENT);
  }

  if (level == 2) {
    #pragma unroll
    for (int mt = 0; mt < 2; ++mt)
      #pragma unroll
      for (int r = 0; r < 4; ++r)
        #pragma unroll
        for (int np = 0; np < 2; ++np)
          rnn_out[(size_t)(wv*32 + mt*16 + akg*4 + r)*512 + stack*256 + wg*32 + 2*lc + np]
              = hmx[mt][np][r];
  }
}

// ---------------- epilogue: elu(rnn@W1+b1)@W2+b2 -> sigmoid ----------------
__global__ __launch_bounds__(256)
void dense_kernel(const float* __restrict__ rnn, const float* __restrict__ W1,
                  const float* __restrict__ b1, const float* __restrict__ W2,
                  const float* __restrict__ b2, float* __restrict__ out) {
  __shared__ float h1[16][64];
  int r0 = blockIdx.x*16;
  int c = threadIdx.x & 63, rr = threadIdx.x >> 6;
  #pragma unroll
  for (int m = 0; m < 4; ++m) {
    int rl = rr*4 + m;
    const float* rp = rnn + (size_t)(r0 + rl)*512;
    float s = b1[c];
    for (int k = 0; k < 512; ++k) s = fmaf(rp[k], W1[(size_t)k*64 + c], s);
    h1[rl][c] = (s > 0.f) ? s : (__expf(s) - 1.f);
  }
  __syncthreads();
  if (threadIdx.x < 96) {
    int rl = threadIdx.x/6, cc = threadIdx.x - rl*6;
    float s = b2[cc];
    #pragma unroll
    for (int k = 0; k < 64; ++k) s = fmaf(h1[rl][k], W2[k*6 + cc], s);
    out[(size_t)(r0 + rl)*6 + cc] = 1.f/(1.f + __expf(-s));
  }
}

// ---------------- launch ----------------
extern "C" void kernel_launch(void* const* d_in, const int* in_sizes, int n_in,
                              void* d_out, int out_size, void* d_ws, size_t ws_size,
                              hipStream_t stream) {
  if (ws_size < WS_NEED) return;  // clean failure instead of corruption
  const int*   words = (const int*)d_in[0];
  const int*   caps  = (const int*)d_in[1];
  const float* emb   = (const float*)d_in[2];
  const float* capt  = (const float*)d_in[3];
  char* ws = (char*)d_ws;
  f16*   xcat  = (f16*)  (ws + OFF_XCAT);
  f16*   wpack = (f16*)  (ws + OFF_WPACK);
  float* bpack = (float*)(ws + OFF_BPACK);
  f16*   hnext = (f16*)  (ws + OFF_HNEXT);
  f16*   hloc  = (f16*)  (ws + OFF_HLOC);
  int*   flags = (int*)  (ws + OFF_FLAGS);
  float* rnn   = (float*)(ws + OFF_RNN);

  embed_kernel<<<TSTEPS*NB, 256, 0, stream>>>(words, caps, emb, capt, xcat);
  pack_kernel<<<6*8*128, 256, 0, stream>>>(
      (const float*)d_in[4],  (const float*)d_in[5],  (const float*)d_in[6],  (const float*)d_in[7],
      (const float*)d_in[8],  (const float*)d_in[9],  (const float*)d_in[10], (const float*)d_in[11],
      (const float*)d_in[12], (const float*)d_in[13], (const float*)d_in[14], (const float*)d_in[15],
      wpack, bpack);
  init_kernel<<<768, 256, 0, stream>>>(flags, hnext);
  lstm_pipeline<<<64, 256, 131072, stream>>>(xcat, wpack, bpack, hnext, hloc, flags, rnn);
  dense_kernel<<<8, 256, 0, stream>>>(rnn, (const float*)d_in[16], (const float*)d_in[17],
                                      (const float*)d_in[18], (const float*)d_in[19], (float*)d_out);
}

// Round 6
// 5342.843 us; speedup vs baseline: 1.8668x; 1.1872x over previous
//
#include <hip/hip_runtime.h>
#include <stdint.h>

#define TSTEPS 500
#define NB 128
#define NH 256
#define RINGN 8

typedef _Float16 f16;
typedef _Float16 f16x8 __attribute__((ext_vector_type(8)));
typedef float f32x4 __attribute__((ext_vector_type(4)));
typedef unsigned long long u64;
typedef unsigned int u32;

// ---------------- workspace layout ----------------
static constexpr size_t HSLOT = (size_t)NB*NH;                    // 32768 f16 per (layer,t) slot
static constexpr size_t SZ_XCAT  = (size_t)TSTEPS*NB*256*2;       // 32.77 MB
static constexpr size_t SZ_WPACK = (size_t)6*8*128*512*2;         // 6.29 MB
static constexpr size_t SZ_BPACK = (size_t)6*8*128*4;
static constexpr size_t SZ_HNEXT = (size_t)6*RINGN*HSLOT*2;       // 3.15 MB (MALL-coherent ring)
static constexpr size_t SZ_HLOC  = (size_t)6*RINGN*HSLOT*2;       // 3.15 MB (XCD-local L2 ring)
static constexpr size_t SZ_FLAG  = (size_t)6*(TSTEPS+1)*32*4;     // per-wave flags, value = xcc+1
static constexpr size_t SZ_RNN   = (size_t)NB*512*4;
static constexpr size_t OFF_XCAT  = 0;
static constexpr size_t OFF_WPACK = OFF_XCAT + SZ_XCAT;
static constexpr size_t OFF_BPACK = OFF_WPACK + SZ_WPACK;
static constexpr size_t OFF_HNEXT = OFF_BPACK + SZ_BPACK;
static constexpr size_t OFF_HLOC  = OFF_HNEXT + SZ_HNEXT;
static constexpr size_t OFF_FLAGL = OFF_HLOC + SZ_HLOC;
static constexpr size_t OFF_FLAGN = OFF_FLAGL + SZ_FLAG;
static constexpr size_t OFF_RNN   = (OFF_FLAGN + SZ_FLAG + 255) & ~(size_t)255;
static constexpr size_t WS_NEED   = OFF_RNN + SZ_RNN;             // ~46.5 MB (R5-proven budget)

// ---------------- prep: embed + concat + pad, cast f16 ----------------
__global__ void embed_kernel(const int* __restrict__ words,
                             const int* __restrict__ caps,
                             const float* __restrict__ emb,
                             const float* __restrict__ capt,
                             f16* __restrict__ xcat) {
  int t = blockIdx.x >> 7, b = blockIdx.x & 127, k = threadIdx.x;
  int w  = words[b*TSTEPS + t];
  int cp = caps [b*TSTEPS + t];
  float v = 0.f;
  if (k < 200)      v = emb[(size_t)w*200 + k];
  else if (k < 203) v = capt[cp*3 + (k-200)];
  xcat[((size_t)t*NB + b)*256 + k] = (f16)v;
}

// ---------------- prep: pack weights per (layer,wg) (R5, proven) ----------------
__global__ void pack_kernel(const float* __restrict__ Wf0, const float* __restrict__ bf0,
                            const float* __restrict__ Wf1, const float* __restrict__ bf1,
                            const float* __restrict__ Wf2, const float* __restrict__ bf2,
                            const float* __restrict__ Wb0, const float* __restrict__ bb0,
                            const float* __restrict__ Wb1, const float* __restrict__ bb1,
                            const float* __restrict__ Wb2, const float* __restrict__ bb2,
                            f16* __restrict__ wpack, float* __restrict__ bpack) {
  int bid = blockIdx.x;
  int n = bid & 127, wg = (bid >> 7) & 7, layer = bid >> 10;
  const float* W; const float* bb;
  switch (layer) {
    case 0: W = Wf0; bb = bf0; break;
    case 1: W = Wf1; bb = bf1; break;
    case 2: W = Wf2; bb = bf2; break;
    case 3: W = Wb0; bb = bb0; break;
    case 4: W = Wb1; bb = bb1; break;
    default: W = Wb2; bb = bb2; break;
  }
  int level = layer % 3;
  int nt = n >> 4, lcn = n & 15;
  int gate = nt >> 1, np = nt & 1;
  int col = gate*256 + wg*32 + 2*lcn + np;
  if (threadIdx.x == 0)
    bpack[((layer*8 + wg) << 7) + n] = bb[col] + (gate == 2 ? 1.f : 0.f);
  size_t base = ((size_t)(layer*8 + wg)*128 + n)*512;
  for (int k = threadIdx.x; k < 512; k += 256) {
    int row;
    if (level == 0) row = (k < 203) ? k : ((k < 256) ? -1 : k - 53);
    else            row = k;
    float v = (row < 0) ? 0.f : W[(size_t)row*1024 + col];
    int idx = (((k >> 3) ^ (n & 7)) << 3) + (k & 7);
    wpack[base + idx] = (f16)v;
  }
}

// ---------------- prep: flags + hnext ring slot0 = h_0 = 0 ----------------
__global__ void init_kernel(int* __restrict__ flagL, int* __restrict__ flagN,
                            f16* __restrict__ hnext) {
  int i = blockIdx.x*256 + threadIdx.x;
  if (i < 6*(TSTEPS+1)*32) {
    int t = (i >> 5) % (TSTEPS+1);
    flagL[i] = 0;                                  // fast path impossible until first post
    flagN[i] = (t == 0) ? 9 : 0;                   // 9 = ready, never matches xcc+1 in [1,8]
  }
  if (i < 98304) {                                 // hnext slot 0 = zeros per layer
    int l = i >> 14, e = i & 16383;
    ((u32*)(hnext + (size_t)l*RINGN*HSLOT))[e] = 0u;
  }
}

// ---------------- helpers ----------------
__device__ __forceinline__ int poll_agent(const int* q) {     // replicated 8 slots over 64 lanes
  int v;
  for (;;) {
    v = __hip_atomic_load(q, __ATOMIC_RELAXED, __HIP_MEMORY_SCOPE_AGENT);
    if (__all(v != 0)) break;
    __builtin_amdgcn_s_sleep(1);
  }
  return v;
}
__device__ __forceinline__ int ld_flag_l(const int* p) {      // sc0: L1-bypass, shared-L2 read
  int v;
  asm volatile("global_load_dword %0, %1, off sc0\n\ts_waitcnt vmcnt(0)"
               : "=v"(v) : "v"(p) : "memory");
  return v;
}
__device__ __forceinline__ f16x8 ld_a_l(const f16* p) {       // 16B same-XCD L2 load
  f16x8 v;
  asm volatile("global_load_dwordx4 %0, %1, off sc0" : "=v"(v) : "v"(p));
  return v;
}
__device__ __forceinline__ f16x8 ldA_coh(const f16* p) {      // cross-XCD via MALL (R2-proven)
  union { u64 q[2]; f16x8 v; } u;
  u.q[0] = __hip_atomic_load((const u64*)p,     __ATOMIC_RELAXED, __HIP_MEMORY_SCOPE_AGENT);
  u.q[1] = __hip_atomic_load((const u64*)p + 1, __ATOMIC_RELAXED, __HIP_MEMORY_SCOPE_AGENT);
  return u.v;
}
__device__ __forceinline__ void st_flag_plain(int* p, int v) {
  asm volatile("global_store_dword %0, %1, off" :: "v"(p), "v"(v) : "memory");
}
__device__ __forceinline__ void vm_drain() {
  asm volatile("s_waitcnt vmcnt(0)" ::: "memory");
  __builtin_amdgcn_sched_barrier(0);
}
__device__ __forceinline__ void vm_wait16() {                 // oldest-16 (aH) complete
  asm volatile("s_waitcnt vmcnt(16)" ::: "memory");
  __builtin_amdgcn_sched_barrier(0);
}
__device__ __forceinline__ void vm_wait8() {                  // oldest-8 (hloc) complete
  asm volatile("s_waitcnt vmcnt(8)" ::: "memory");
  __builtin_amdgcn_sched_barrier(0);
}
__device__ __forceinline__ u32 packh2(float a, float b) {
  union { f16 h[2]; u32 u; } x;
  x.h[0] = (f16)a; x.h[1] = (f16)b;
  return x.u;
}
__device__ __forceinline__ float sigf(float x) { return 1.f/(1.f + __expf(-x)); }
__device__ __forceinline__ float tanhf_(float x) {
  float e = __expf(-2.f*fabsf(x));
  float r = (1.f - e)/(1.f + e);
  return x < 0.f ? -r : r;
}

// grid = 64 (blockIdx = wg*8 + layer; layer>=6 exits), block = 256 (4 waves), dynLDS = 128KB.
// Wave wv owns rows [wv*32,+32) x ALL 128 gate-cols; the 4 wv-cohorts are independent pipelines.
// Recurrence sync: flagL (plain store -> shared L2, sc0 poll, value==own xcc+1 validates same-XCD)
// with per-spin flagN (MALL) fallback -> deadlock-free under any placement.
__global__ __launch_bounds__(256, 1)
void lstm_pipeline(const f16* __restrict__ xcat, const f16* __restrict__ wpack,
                   const float* __restrict__ bpack, f16* hnext, f16* hloc,
                   int* flagL, int* flagN, float* __restrict__ rnn_out) {
  const int layer = blockIdx.x & 7, wg = blockIdx.x >> 3;
  if (layer >= 6) return;
  extern __shared__ char smem[];
  const int stack = layer/3, level = layer - stack*3;

  { // weights -> LDS (swizzled image, linear copy)
    const uint4* src = (const uint4*)(wpack + (size_t)(layer*8 + wg)*128*512);
    uint4* dst = (uint4*)smem;
    for (int i = threadIdx.x; i < 8192; i += 256) dst[i] = src[i];
  }
  const int lane = threadIdx.x & 63, wv = threadIdx.x >> 6;
  const int lc = lane & 15, akg = lane >> 4, bx = lc & 7;
  const int lw = (lane & 7)*4 + wv;                 // replicated flag-slot index (8 WGs x wv)
  const int xcp1 = ((int)__builtin_amdgcn_s_getreg((31 << 11) | 20) & 7) + 1;  // HW_REG_XCC_ID

  float bI[2], bJ[2], bF[2], bO[2];
  {
    const float* bb = bpack + ((size_t)(layer*8 + wg) << 7);
    #pragma unroll
    for (int np = 0; np < 2; ++np) {
      bI[np] = bb[(0*2 + np)*16 + lc];
      bJ[np] = bb[(1*2 + np)*16 + lc];
      bF[np] = bb[(2*2 + np)*16 + lc];
      bO[np] = bb[(3*2 + np)*16 + lc];
    }
  }
  __syncthreads();

  int*       flL  = flagL + (size_t)layer*(TSTEPS+1)*32;
  int*       flN  = flagN + (size_t)layer*(TSTEPS+1)*32;
  const int* flNp = flagN + (size_t)(layer-1)*(TSTEPS+1)*32;
  const int* flNn = flagN + (size_t)(layer+1)*(TSTEPS+1)*32;

  const size_t aoffL = ((size_t)(wv*32 + lc))*256 + (size_t)akg*8;

  float c_st[2][2][4], hmx[2][2][4];
  #pragma unroll
  for (int mt = 0; mt < 2; ++mt)
    #pragma unroll
    for (int np = 0; np < 2; ++np)
      #pragma unroll
      for (int r = 0; r < 4; ++r) { c_st[mt][np][r] = 0.f; hmx[mt][np][r] = -2.f; }

  bool prev_l2 = false;

  for (int t = 1; t <= TSTEPS; ++t) {
    // A. batched prev-layer poll (lookahead +3, every 4 steps); also fixes aI source
    if (level && (t & 3) == 1) {
      int tt = (t + 3 > TSTEPS) ? TSTEPS : t + 3;
      int v = poll_agent(flNp + (size_t)tt*32 + lw);
      prev_l2 = __all(v == xcp1);
    }
    // B. backpressure (ring 8): consumer must have finished t-5; every 2 steps
    if (level < 2 && t >= 8 && (t & 1) == 0)
      poll_agent(flNn + (size_t)(t-5)*32 + lw);

    // C. own-poll(t-1): sc0/L2 fast path, MALL fallback each spin (liveness-safe)
    bool fast;
    {
      const int* qL = flL + (size_t)(t-1)*32 + lw;
      const int* qN = flN + (size_t)(t-1)*32 + lw;
      for (;;) {
        int vL = ld_flag_l(qL);                     // includes vmcnt(0): drains old flagN store
        if (__all(vL == xcp1)) { fast = true; break; }
        int vN = __hip_atomic_load(qN, __ATOMIC_RELAXED, __HIP_MEMORY_SCOPE_AGENT);
        if (__all(vN != 0)) { fast = false; break; }
        __builtin_amdgcn_s_sleep(1);
      }
    }
    __builtin_amdgcn_sched_barrier(0);

    // D. issue aH (own h_{t-1}): 16 loads, FIRST in vm queue
    f16x8 aH0[8], aH1[8];
    {
      const size_t off = ((size_t)layer*RINGN + (size_t)((t-1) & (RINGN-1)))*HSLOT + aoffL;
      if (fast) {
        const f16* A = hloc + off;
        #pragma unroll
        for (int k8 = 0; k8 < 8; ++k8) {
          aH0[k8] = ld_a_l(A + k8*32);
          aH1[k8] = ld_a_l(A + 16*256 + k8*32);
        }
      } else {
        const f16* A = hnext + off;
        #pragma unroll
        for (int k8 = 0; k8 < 8; ++k8) {
          aH0[k8] = ldA_coh(A + k8*32);
          aH1[k8] = ldA_coh(A + 16*256 + k8*32);
        }
      }
    }
    __builtin_amdgcn_sched_barrier(0);

    // E. issue aI (input h / xcat): 16 loads, SECOND in vm queue
    f16x8 aI0[8], aI1[8];
    if (level == 0) {
      const f16* A = xcat + (size_t)(stack ? (TSTEPS - t) : (t-1))*NB*256 + aoffL;
      #pragma unroll
      for (int k8 = 0; k8 < 8; ++k8) {
        aI0[k8] = *(const f16x8*)(A + k8*32);
        aI1[k8] = *(const f16x8*)(A + 16*256 + k8*32);
      }
    } else {
      const size_t off = ((size_t)(layer-1)*RINGN + (size_t)(t & (RINGN-1)))*HSLOT + aoffL;
      if (prev_l2) {
        const f16* A = hloc + off;
        #pragma unroll
        for (int k8 = 0; k8 < 8; ++k8) {
          aI0[k8] = ld_a_l(A + k8*32);
          aI1[k8] = ld_a_l(A + 16*256 + k8*32);
        }
      } else {
        const f16* A = hnext + off;
        #pragma unroll
        for (int k8 = 0; k8 < 8; ++k8) {
          aI0[k8] = ldA_coh(A + k8*32);
          aI1[k8] = ldA_coh(A + 16*256 + k8*32);
        }
      }
    }
    __builtin_amdgcn_sched_barrier(0);

    // F. wait aH only (FIFO oldest-16), rec-half GEMM hides aI's MALL latency
    vm_wait16();

    f32x4 acc[2][8];
    #pragma unroll
    for (int mt = 0; mt < 2; ++mt)
      #pragma unroll
      for (int nt = 0; nt < 8; ++nt) acc[mt][nt] = (f32x4){0.f,0.f,0.f,0.f};

    #pragma unroll
    for (int k8 = 0; k8 < 8; ++k8) {                  // recurrent half (kword 32..63)
      const int swz1 = ((32 + k8*4 + akg) ^ bx) << 4;
      #pragma unroll
      for (int nt = 0; nt < 8; ++nt) {
        f16x8 vb1 = *(const f16x8*)(smem + (nt*16 + lc)*1024 + swz1);
        acc[0][nt] = __builtin_amdgcn_mfma_f32_16x16x32_f16(aH0[k8], vb1, acc[0][nt], 0,0,0);
        acc[1][nt] = __builtin_amdgcn_mfma_f32_16x16x32_f16(aH1[k8], vb1, acc[1][nt], 0,0,0);
      }
    }

    // G. wait aI, input-half GEMM
    vm_drain();
    #pragma unroll
    for (int k8 = 0; k8 < 8; ++k8) {                  // input half (kword 0..31)
      const int swz0 = ((k8*4 + akg) ^ bx) << 4;
      #pragma unroll
      for (int nt = 0; nt < 8; ++nt) {
        f16x8 vb0 = *(const f16x8*)(smem + (nt*16 + lc)*1024 + swz0);
        acc[0][nt] = __builtin_amdgcn_mfma_f32_16x16x32_f16(aI0[k8], vb0, acc[0][nt], 0,0,0);
        acc[1][nt] = __builtin_amdgcn_mfma_f32_16x16x32_f16(aI1[k8], vb0, acc[1][nt], 0,0,0);
      }
    }

    // H. cell update (lane-local) into packed registers
    u32 pk[2][4];
    #pragma unroll
    for (int mt = 0; mt < 2; ++mt) {
      #pragma unroll
      for (int r = 0; r < 4; ++r) {
        float hv[2];
        #pragma unroll
        for (int np = 0; np < 2; ++np) {
          float zi = acc[mt][0 + np][r] + bI[np];
          float zj = acc[mt][2 + np][r] + bJ[np];
          float zf = acc[mt][4 + np][r] + bF[np];      // +1 already folded
          float zo = acc[mt][6 + np][r] + bO[np];
          float cs = sigf(zf)*c_st[mt][np][r] + sigf(zi)*tanhf_(zj);
          c_st[mt][np][r] = cs;
          float h = sigf(zo)*tanhf_(cs);
          hv[np] = h;
          if (level == 2) hmx[mt][np][r] = fmaxf(hmx[mt][np][r], h);
        }
        pk[mt][r] = packh2(hv[0], hv[1]);
      }
    }

    // I. stores: 8 hloc (L2) first, 8 hnext (MALL) second; vmcnt(8) waits hloc only
    {
      const size_t obase = ((size_t)layer*RINGN + (size_t)(t & (RINGN-1)))*HSLOT;
      u32* hl32 = (u32*)(hloc  + obase);
      u32* hn32 = (u32*)(hnext + obase);
      #pragma unroll
      for (int mt = 0; mt < 2; ++mt)
        #pragma unroll
        for (int r = 0; r < 4; ++r) {
          int row = wv*32 + mt*16 + akg*4 + r;
          hl32[(size_t)row*128 + wg*16 + lc] = pk[mt][r];
        }
      asm volatile("" ::: "memory");                  // IR fence: keep hloc before hnext
      __builtin_amdgcn_sched_barrier(0);
      #pragma unroll
      for (int mt = 0; mt < 2; ++mt)
        #pragma unroll
        for (int r = 0; r < 4; ++r) {
          int row = wv*32 + mt*16 + akg*4 + r;
          __hip_atomic_store(&hn32[(size_t)row*128 + wg*16 + lc], pk[mt][r],
                             __ATOMIC_RELAXED, __HIP_MEMORY_SCOPE_AGENT);
        }
      __builtin_amdgcn_sched_barrier(0);
    }
    vm_wait8();                                       // hloc visible in L2
    if (lane == 0) st_flag_plain(flL + (size_t)t*32 + wg*4 + wv, xcp1);
    vm_drain();                                       // hnext acked at MALL
    if (lane == 0)
      __hip_atomic_store(flN + (size_t)t*32 + wg*4 + wv, xcp1,
                         __ATOMIC_RELAXED, __HIP_MEMORY_SCOPE_AGENT);
  }

  if (level == 2) {
    #pragma unroll
    for (int mt = 0; mt < 2; ++mt)
      #pragma unroll
      for (int r = 0; r < 4; ++r)
        #pragma unroll
        for (int np = 0; np < 2; ++np)
          rnn_out[(size_t)(wv*32 + mt*16 + akg*4 + r)*512 + stack*256 + wg*32 + 2*lc + np]
              = hmx[mt][np][r];
  }
}

// ---------------- epilogue: elu(rnn@W1+b1)@W2+b2 -> sigmoid ----------------
__global__ __launch_bounds__(256)
void dense_kernel(const float* __restrict__ rnn, const float* __restrict__ W1,
                  const float* __restrict__ b1, const float* __restrict__ W2,
                  const float* __restrict__ b2, float* __restrict__ out) {
  __shared__ float h1[16][64];
  int r0 = blockIdx.x*16;
  int c = threadIdx.x & 63, rr = threadIdx.x >> 6;
  #pragma unroll
  for (int m = 0; m < 4; ++m) {
    int rl = rr*4 + m;
    const float* rp = rnn + (size_t)(r0 + rl)*512;
    float s = b1[c];
    for (int k = 0; k < 512; ++k) s = fmaf(rp[k], W1[(size_t)k*64 + c], s);
    h1[rl][c] = (s > 0.f) ? s : (__expf(s) - 1.f);
  }
  __syncthreads();
  if (threadIdx.x < 96) {
    int rl = threadIdx.x/6, cc = threadIdx.x - rl*6;
    float s = b2[cc];
    #pragma unroll
    for (int k = 0; k < 64; ++k) s = fmaf(h1[rl][k], W2[k*6 + cc], s);
    out[(size_t)(r0 + rl)*6 + cc] = 1.f/(1.f + __expf(-s));
  }
}

// ---------------- launch ----------------
extern "C" void kernel_launch(void* const* d_in, const int* in_sizes, int n_in,
                              void* d_out, int out_size, void* d_ws, size_t ws_size,
                              hipStream_t stream) {
  if (ws_size < WS_NEED) return;  // clean failure instead of corruption
  const int*   words = (const int*)d_in[0];
  const int*   caps  = (const int*)d_in[1];
  const float* emb   = (const float*)d_in[2];
  const float* capt  = (const float*)d_in[3];
  char* ws = (char*)d_ws;
  f16*   xcat  = (f16*)  (ws + OFF_XCAT);
  f16*   wpack = (f16*)  (ws + OFF_WPACK);
  float* bpack = (float*)(ws + OFF_BPACK);
  f16*   hnext = (f16*)  (ws + OFF_HNEXT);
  f16*   hloc  = (f16*)  (ws + OFF_HLOC);
  int*   flagL = (int*)  (ws + OFF_FLAGL);
  int*   flagN = (int*)  (ws + OFF_FLAGN);
  float* rnn   = (float*)(ws + OFF_RNN);

  embed_kernel<<<TSTEPS*NB, 256, 0, stream>>>(words, caps, emb, capt, xcat);
  pack_kernel<<<6*8*128, 256, 0, stream>>>(
      (const float*)d_in[4],  (const float*)d_in[5],  (const float*)d_in[6],  (const float*)d_in[7],
      (const float*)d_in[8],  (const float*)d_in[9],  (const float*)d_in[10], (const float*)d_in[11],
      (const float*)d_in[12], (const float*)d_in[13], (const float*)d_in[14], (const float*)d_in[15],
      wpack, bpack);
  init_kernel<<<768, 256, 0, stream>>>(flagL, flagN, hnext);
  lstm_pipeline<<<64, 256, 131072, stream>>>(xcat, wpack, bpack, hnext, hloc,
                                             flagL, flagN, rnn);
  dense_kernel<<<8, 256, 0, stream>>>(rnn, (const float*)d_in[16], (const float*)d_in[17],
                                      (const float*)d_in[18], (const float*)d_in[19], (float*)d_out);
}